// Round 7
// baseline (1316.010 us; speedup 1.0000x reference)
//
#include <hip/hip_runtime.h>

#define WALK 16
#define HID 64

// ---------------- new fast path params ----------------
#define CH1 8192       // sort chunk (edges)
#define RBSH 7         // pass-1 key: row block = 128 rows
#define CBSH 11        // pass-2 key: col bucket = 2048 cols
#define CB 2048
#define SLICES 20      // step parallel slices per col bucket
#define MAXRB 1024     // RBK <= 1024  (N <= 131072)
#define MAXCB 64       // NB2 <= 64

// ---------------- R6 fallback params ----------------
#define CHUNK 16384
#define BSH 7
#define MAXB 808

// ===========================================================================
// R7: edges sorted by (col_bucket[2048], row_block[128]) via two counting-sort
// passes -> step gathers hit ~8 cache lines/wave instead of 64 (R6 steps were
// ~69us each vs ~12us stream floor; gather address divergence + convoying).
// Steps: 49x20 blocks, 8KB LDS acc, partial sums + reduce kernel (self-loop,
// dinv). deg free from the row-sorted pass-1 intermediate. Global atomics
// remain banned on the hot path (fabric-wall ~20 G/s, R1-R3 measured).
//
// Packing (intermediate buf1): lo = row | (col&0x7FFF)<<17 ; hi = (w&~3)|(col>>15)
// Packing (final csr):         lo = row | (col&2047)<<17   ; hi = w&~3
// row,col < 2^17; weight loses 2 mantissa LSBs (rel err 3e-7, irrelevant).
//
// ws (words): [csr 2E | buf1 2E | bptr1 RBK+1 | tot1 RBK | bptr2 NB2+1 |
//              tot2 NB2 | dinv N | qA N | qB N | probs 16N]
// overlays: C1 (NW*RBK) in csr region (dead before pass-2 writes csr);
//           C2 (NW*NB2) in probs; part (NB2*SLICES*2048) in buf1 (dead after
//           pass 2). need ~= (4E + 19N) * 4 bytes.
// ===========================================================================

// ---------------- shared scan kernels ----------------

__global__ __launch_bounds__(256) void colscan_k(int* __restrict__ C,
                                                 int* __restrict__ tot,
                                                 int NBKT, int NW) {
    int b = blockIdx.x * 256 + threadIdx.x;
    if (b >= NBKT) return;
    int run = 0;
    for (int w = 0; w < NW; ++w) {
        size_t idx = (size_t)w * NBKT + b;
        int t = C[idx];
        C[idx] = run;
        run += t;
    }
    tot[b] = run;
}

__global__ __launch_bounds__(1024) void bktscan_k(const int* __restrict__ tot,
                                                  int* __restrict__ ptr,
                                                  int NBKT, int E) {
    __shared__ int wsum[16];
    __shared__ int carry_s;
    int tid = threadIdx.x, lane = tid & 63, wid = tid >> 6;
    if (tid == 0) carry_s = 0;
    __syncthreads();
    for (int base = 0; base < NBKT; base += 1024) {
        int x = (base + tid < NBKT) ? tot[base + tid] : 0;
        int v = x;
        #pragma unroll
        for (int d = 1; d < 64; d <<= 1) { int t = __shfl_up(v, d); if (lane >= d) v += t; }
        __syncthreads();
        if (lane == 63) wsum[wid] = v;
        __syncthreads();
        if (tid < 16) {
            int sv = wsum[tid];
            #pragma unroll
            for (int d = 1; d < 16; d <<= 1) { int t = __shfl_up(sv, d); if (tid >= d) sv += t; }
            wsum[tid] = sv;
        }
        __syncthreads();
        int woff = wid ? wsum[wid - 1] : 0;
        int carry = carry_s;
        if (base + tid < NBKT) ptr[base + tid] = carry + woff + v - x;
        __syncthreads();
        if (tid == 0) carry_s = carry + wsum[15];
    }
    if (tid == 0) ptr[NBKT] = E;
}

// ---------------- pass 1: sort by row>>7 ----------------

__global__ __launch_bounds__(256) void p1hist_k(const int* __restrict__ ei,
                                                int* __restrict__ C1,
                                                int RBK, int E) {
    __shared__ int cnt[MAXRB];
    int w = blockIdx.x, tid = threadIdx.x;
    for (int b = tid; b < RBK; b += 256) cnt[b] = 0;
    __syncthreads();
    int s = w * CH1, m = min(E - s, CH1);
    int vec = m & ~3;
    for (int off = 4 * tid; off < vec; off += 1024) {
        int4 r4 = *(const int4*)(ei + s + off);
        atomicAdd(&cnt[r4.x >> RBSH], 1);
        atomicAdd(&cnt[r4.y >> RBSH], 1);
        atomicAdd(&cnt[r4.z >> RBSH], 1);
        atomicAdd(&cnt[r4.w >> RBSH], 1);
    }
    for (int off = vec + tid; off < m; off += 256)
        atomicAdd(&cnt[ei[s + off] >> RBSH], 1);
    __syncthreads();
    for (int b = tid; b < RBK; b += 256) C1[(size_t)w * RBK + b] = cnt[b];
}

__global__ __launch_bounds__(1024) void p1scat_k(const int* __restrict__ ei,
                                                 const float* __restrict__ ew,
                                                 const int* __restrict__ C1,
                                                 const int* __restrict__ bptr1,
                                                 uint2* __restrict__ buf1,
                                                 int RBK, int E) {
    __shared__ uint2 stg[CH1];                 // 64 KB
    __shared__ int cnt[MAXRB];
    __shared__ int pfx[MAXRB + 1];
    __shared__ int rbs[MAXRB];
    __shared__ int wsum[16];
    int w = blockIdx.x, tid = threadIdx.x, lane = tid & 63, wid = tid >> 6;
    int s = w * CH1, m = min(E - s, CH1);

    int rr[8]; unsigned cc[8], wb[8];
    for (int b = tid; b < RBK; b += 1024) cnt[b] = 0;
    __syncthreads();
    #pragma unroll
    for (int i = 0; i < 8; ++i) {
        int off = tid + i * 1024;
        bool ok = off < m;
        int r = 0, c = 0; float v = 0.0f;
        if (ok) { r = ei[s + off]; c = ei[E + s + off]; v = ew[s + off]; }
        rr[i] = r; cc[i] = (unsigned)c; wb[i] = __float_as_uint(v);
        if (ok) atomicAdd(&cnt[r >> RBSH], 1);
    }
    __syncthreads();
    {   // block scan over RBK (<=1024) buckets
        int x = (tid < RBK) ? cnt[tid] : 0;
        int v = x;
        #pragma unroll
        for (int d = 1; d < 64; d <<= 1) { int t = __shfl_up(v, d); if (lane >= d) v += t; }
        if (lane == 63) wsum[wid] = v;
        __syncthreads();
        if (tid < 16) {
            int sv = wsum[tid];
            #pragma unroll
            for (int d = 1; d < 16; d <<= 1) { int t = __shfl_up(sv, d); if (tid >= d) sv += t; }
            wsum[tid] = sv;
        }
        __syncthreads();
        int excl = (wid ? wsum[wid - 1] : 0) + v - x;
        if (tid < RBK) {
            pfx[tid] = excl;
            rbs[tid] = bptr1[tid] + C1[(size_t)w * RBK + tid] - excl;
            cnt[tid] = 0;
        }
        if (tid == 0) pfx[RBK] = m;
    }
    __syncthreads();
    #pragma unroll
    for (int i = 0; i < 8; ++i) {
        int off = tid + i * 1024;
        if (off < m) {
            int b = rr[i] >> RBSH;
            int l = atomicAdd(&cnt[b], 1);
            stg[pfx[b] + l] = make_uint2((unsigned)rr[i] | ((cc[i] & 0x7FFFu) << 17),
                                         (wb[i] & ~3u) | (cc[i] >> 15));
        }
    }
    __syncthreads();
    for (int j = tid; j < m; j += 1024) {
        int lo = 0, hi = RBK;
        while (hi - lo > 1) { int mid = (lo + hi) >> 1; if (pfx[mid] <= j) lo = mid; else hi = mid; }
        buf1[(size_t)(rbs[lo] + j)] = stg[j];
    }
}

// ---- deg from row-sorted buf1: coalesced stream + 128-slot LDS acc ----
__global__ __launch_bounds__(256) void deg2_k(const uint2* __restrict__ buf1,
                                              const int* __restrict__ bptr1,
                                              float* __restrict__ dinv,
                                              float* __restrict__ q0, int N) {
    __shared__ float acc[128];
    int rb = blockIdx.x, tid = threadIdx.x;
    if (tid < 128) acc[tid] = 0.0f;
    __syncthreads();
    int s = bptr1[rb], e = bptr1[rb + 1];
    for (int i = s + tid; i < e; i += 256) {
        uint2 t = buf1[i];
        atomicAdd(&acc[t.x & 127], __uint_as_float(t.y & ~3u));
    }
    __syncthreads();
    if (tid < 128) {
        int r = rb * 128 + tid;
        if (r < N) {
            float dv = 1.0f / fmaxf(acc[tid] + 1.0f, 1e-8f);   // +1 self-loop
            dinv[r] = dv;
            q0[r] = dv;                                        // prob0 = 1
        }
    }
}

// ---------------- pass 2: stable sort by col>>11 ----------------

__global__ __launch_bounds__(256) void p2hist_k(const uint2* __restrict__ buf1,
                                                int* __restrict__ C2,
                                                int NB2, int E) {
    __shared__ int cnt[MAXCB];
    int w = blockIdx.x, tid = threadIdx.x;
    if (tid < MAXCB) cnt[tid] = 0;
    __syncthreads();
    int s = w * CH1, m = min(E - s, CH1);
    for (int off = tid; off < m; off += 256) {
        uint2 t = buf1[s + off];
        unsigned col = (t.x >> 17) | ((t.y & 3u) << 15);
        atomicAdd(&cnt[col >> CBSH], 1);
    }
    __syncthreads();
    if (tid < NB2) C2[(size_t)w * NB2 + tid] = cnt[tid];
}

__global__ __launch_bounds__(1024) void p2scat_k(const uint2* __restrict__ buf1,
                                                 const int* __restrict__ C2,
                                                 const int* __restrict__ bptr2,
                                                 uint2* __restrict__ csr,
                                                 int NB2, int E) {
    __shared__ uint2 stg[CH1];
    __shared__ int cnt[MAXCB];
    __shared__ int pfx[MAXCB + 1];
    __shared__ int rbs[MAXCB];
    int w = blockIdx.x, tid = threadIdx.x;
    int s = w * CH1, m = min(E - s, CH1);

    uint2 tt[8]; int bb[8];
    if (tid < MAXCB) cnt[tid] = 0;
    __syncthreads();
    #pragma unroll
    for (int i = 0; i < 8; ++i) {
        int off = tid + i * 1024;
        uint2 t = make_uint2(0, 0);
        int b = 0;
        if (off < m) {
            t = buf1[s + off];
            unsigned col = (t.x >> 17) | ((t.y & 3u) << 15);
            b = (int)(col >> CBSH);
            atomicAdd(&cnt[b], 1);
        }
        tt[i] = t; bb[i] = b;
    }
    __syncthreads();
    if (tid < 64) {   // wave-0 scan over 64 bucket slots
        int x = cnt[tid];
        int v = x;
        #pragma unroll
        for (int d = 1; d < 64; d <<= 1) { int t = __shfl_up(v, d); if (tid >= d) v += t; }
        pfx[tid] = v - x;
        if (tid < NB2) rbs[tid] = bptr2[tid] + C2[(size_t)w * NB2 + tid] - (v - x);
        cnt[tid] = 0;
        if (tid == 63) pfx[64] = v;
    }
    __syncthreads();
    #pragma unroll
    for (int i = 0; i < 8; ++i) {
        int off = tid + i * 1024;
        if (off < m) {
            int b = bb[i];
            int l = atomicAdd(&cnt[b], 1);
            unsigned col = (tt[i].x >> 17) | ((tt[i].y & 3u) << 15);
            unsigned row = tt[i].x & 0x1FFFFu;
            stg[pfx[b] + l] = make_uint2(row | ((col & 2047u) << 17), tt[i].y & ~3u);
        }
    }
    __syncthreads();
    for (int j = tid; j < m; j += 1024) {
        int lo = 0, hi = MAXCB;
        while (hi - lo > 1) { int mid = (lo + hi) >> 1; if (pfx[mid] <= j) lo = mid; else hi = mid; }
        csr[(size_t)(rbs[lo] + j)] = stg[j];
    }
}

// ---------------- steps: sliced bucket accumulate + reduce ----------------

__global__ __launch_bounds__(256) void step2_k(const uint2* __restrict__ csr,
                                               const int* __restrict__ bptr2,
                                               const float* __restrict__ q,
                                               float* __restrict__ part) {
    __shared__ float acc[CB];
    int blk = blockIdx.x;
    int b = blk / SLICES, sl = blk % SLICES;
    int tid = threadIdx.x;
    for (int t = tid; t < CB; t += 256) acc[t] = 0.0f;
    __syncthreads();
    int be = bptr2[b], en = bptr2[b + 1], len = en - be;
    int i0 = be + (int)((long long)len * sl / SLICES);
    int i1 = be + (int)((long long)len * (sl + 1) / SLICES);
    int i = i0 + tid;
    for (; i + 768 < i1; i += 1024) {
        uint2 t0 = csr[i], t1 = csr[i + 256], t2 = csr[i + 512], t3 = csr[i + 768];
        float v0 = q[t0.x & 0x1FFFF] * __uint_as_float(t0.y);
        float v1 = q[t1.x & 0x1FFFF] * __uint_as_float(t1.y);
        float v2 = q[t2.x & 0x1FFFF] * __uint_as_float(t2.y);
        float v3 = q[t3.x & 0x1FFFF] * __uint_as_float(t3.y);
        atomicAdd(&acc[t0.x >> 17], v0);
        atomicAdd(&acc[t1.x >> 17], v1);
        atomicAdd(&acc[t2.x >> 17], v2);
        atomicAdd(&acc[t3.x >> 17], v3);
    }
    for (; i < i1; i += 256) {
        uint2 t = csr[i];
        atomicAdd(&acc[t.x >> 17], q[t.x & 0x1FFFF] * __uint_as_float(t.y));
    }
    __syncthreads();
    float* dst = part + (size_t)blk * CB;
    for (int t = tid; t < CB; t += 256) dst[t] = acc[t];
}

__global__ __launch_bounds__(256) void reduce_k(const float* __restrict__ part,
                                                const float* __restrict__ q,
                                                const float* __restrict__ dinv,
                                                float* __restrict__ prob_out,
                                                float* __restrict__ q_out, int N) {
    int c = blockIdx.x * 256 + threadIdx.x;
    if (c >= N) return;
    int b = c >> CBSH, off = c & (CB - 1);
    const float* p = part + (size_t)b * SLICES * CB + off;
    float sum = 0.0f;
    #pragma unroll
    for (int s = 0; s < SLICES; ++s) sum += p[(size_t)s * CB];
    float pr = sum + q[c];          // self-loop: prob[c]*dinv[c] = q[c]
    prob_out[c] = pr;
    q_out[c] = pr * dinv[c];
}

// ---------------- MLP (uniform weight loads, R6-proven) ----------------

__global__ __launch_bounds__(128) void mlp2_kernel(const float* __restrict__ probs,
                                                   const float* __restrict__ W1,
                                                   const float* __restrict__ b1,
                                                   const float* __restrict__ W2,
                                                   const float* __restrict__ b2,
                                                   float* __restrict__ out, int N) {
    int n = blockIdx.x * 128 + threadIdx.x;
    if (n >= N) return;
    float p[WALK];
    #pragma unroll
    for (int k = 0; k < WALK; ++k) p[k] = probs[(size_t)k * N + n];
    float h[HID];
    #pragma unroll
    for (int j = 0; j < HID; ++j) {
        float a = b1[j];
        #pragma unroll
        for (int k = 0; k < WALK; ++k) a += W1[j * WALK + k] * p[k];
        h[j] = fmaxf(a, 0.0f);
    }
    #pragma unroll
    for (int j = 0; j < HID; j += 4) {
        float4 o;
        float* op = (float*)&o;
        #pragma unroll
        for (int qq = 0; qq < 4; ++qq) {
            float a = b2[j + qq];
            #pragma unroll
            for (int k = 0; k < HID; ++k) a += W2[(j + qq) * HID + k] * h[k];
            op[qq] = a;
        }
        *(float4*)&out[(size_t)n * HID + j] = o;
    }
}

// ===========================================================================
// R6 fallback path (proven at 1284 us) — used when ws too small for R7.
// ===========================================================================

__global__ __launch_bounds__(256) void hist_k(const int* __restrict__ ei,
                                              int* __restrict__ Cc,
                                              int* __restrict__ Cr,
                                              int NBKT, int E, int do_row) {
    __shared__ int cntc[MAXB];
    __shared__ int cntr[MAXB];
    int w = blockIdx.x, tid = threadIdx.x;
    for (int b = tid; b < NBKT; b += 256) { cntc[b] = 0; cntr[b] = 0; }
    __syncthreads();
    int s = w * CHUNK;
    int cnt = min(E - s, CHUNK);
    const int* colp = ei + E;
    int vec = ((E & 3) == 0) ? (cnt & ~3) : 0;
    for (int off = 4 * tid; off < vec; off += 1024) {
        int4 c4 = *(const int4*)(colp + s + off);
        atomicAdd(&cntc[c4.x >> BSH], 1);
        atomicAdd(&cntc[c4.y >> BSH], 1);
        atomicAdd(&cntc[c4.z >> BSH], 1);
        atomicAdd(&cntc[c4.w >> BSH], 1);
        if (do_row) {
            int4 r4 = *(const int4*)(ei + s + off);
            atomicAdd(&cntr[r4.x >> BSH], 1);
            atomicAdd(&cntr[r4.y >> BSH], 1);
            atomicAdd(&cntr[r4.z >> BSH], 1);
            atomicAdd(&cntr[r4.w >> BSH], 1);
        }
    }
    for (int off = vec + tid; off < cnt; off += 256) {
        atomicAdd(&cntc[colp[s + off] >> BSH], 1);
        if (do_row) atomicAdd(&cntr[ei[s + off] >> BSH], 1);
    }
    __syncthreads();
    for (int b = tid; b < NBKT; b += 256) {
        Cc[(size_t)w * NBKT + b] = cntc[b];
        if (do_row) Cr[(size_t)w * NBKT + b] = cntr[b];
    }
}

__global__ __launch_bounds__(1024) void scatter_sort_k(const int* __restrict__ ei,
                                                       const float* __restrict__ ew,
                                                       const int* __restrict__ Cc,
                                                       const int* __restrict__ Cr,
                                                       const int* __restrict__ bptrc,
                                                       const int* __restrict__ bptrr,
                                                       uint2* __restrict__ csr,
                                                       unsigned* __restrict__ degp,
                                                       int NBKT, int E, int do_row) {
    __shared__ uint2 stg[CHUNK];
    __shared__ int cnt[MAXB];
    __shared__ int pfx[MAXB + 1];
    __shared__ int rbs[MAXB];
    __shared__ int wsum[16];
    unsigned* ustg = (unsigned*)stg;
    const int w = blockIdx.x, tid = threadIdx.x;
    const int lane = tid & 63, wid = tid >> 6;
    const int s = w * CHUNK;
    const int m = min(E - s, CHUNK);

    int rr[16], cc[16];
    unsigned wb[16];
    for (int b = tid; b < NBKT; b += 1024) cnt[b] = 0;
    __syncthreads();
    #pragma unroll
    for (int i = 0; i < 16; ++i) {
        int off = tid + i * 1024;
        bool ok = off < m;
        int r = 0, c = 0; float v = 0.0f;
        if (ok) { r = ei[s + off]; c = ei[E + s + off]; v = ew[s + off]; }
        rr[i] = r; cc[i] = c; wb[i] = __float_as_uint(v);
        if (ok) atomicAdd(&cnt[c >> BSH], 1);
    }
    __syncthreads();
    {
        int x = (tid < NBKT) ? cnt[tid] : 0;
        int v = x;
        #pragma unroll
        for (int d = 1; d < 64; d <<= 1) { int t = __shfl_up(v, d); if (lane >= d) v += t; }
        if (lane == 63) wsum[wid] = v;
        __syncthreads();
        if (tid < 16) {
            int sv = wsum[tid];
            #pragma unroll
            for (int d = 1; d < 16; d <<= 1) { int t = __shfl_up(sv, d); if (tid >= d) sv += t; }
            wsum[tid] = sv;
        }
        __syncthreads();
        int excl = (wid ? wsum[wid - 1] : 0) + v - x;
        if (tid < NBKT) {
            pfx[tid] = excl;
            rbs[tid] = bptrc[tid] + Cc[(size_t)w * NBKT + tid] - excl;
            cnt[tid] = 0;
        }
        if (tid == 0) pfx[NBKT] = m;
    }
    __syncthreads();
    #pragma unroll
    for (int i = 0; i < 16; ++i) {
        int off = tid + i * 1024;
        if (off < m) {
            int b = cc[i] >> BSH;
            int l = atomicAdd(&cnt[b], 1);
            stg[pfx[b] + l] = make_uint2((unsigned)rr[i] | ((unsigned)(cc[i] & 127) << 25), wb[i]);
        }
    }
    __syncthreads();
    for (int j = tid; j < m; j += 1024) {
        int lo = 0, hi = NBKT;
        while (hi - lo > 1) { int mid = (lo + hi) >> 1; if (pfx[mid] <= j) lo = mid; else hi = mid; }
        csr[(size_t)(rbs[lo] + j)] = stg[j];
    }
    if (!do_row) return;
    __syncthreads();
    for (int b = tid; b < NBKT; b += 1024) cnt[b] = 0;
    __syncthreads();
    #pragma unroll
    for (int i = 0; i < 16; ++i) {
        int off = tid + i * 1024;
        if (off < m) atomicAdd(&cnt[rr[i] >> BSH], 1);
    }
    __syncthreads();
    {
        int x = (tid < NBKT) ? cnt[tid] : 0;
        int v = x;
        #pragma unroll
        for (int d = 1; d < 64; d <<= 1) { int t = __shfl_up(v, d); if (lane >= d) v += t; }
        if (lane == 63) wsum[wid] = v;
        __syncthreads();
        if (tid < 16) {
            int sv = wsum[tid];
            #pragma unroll
            for (int d = 1; d < 16; d <<= 1) { int t = __shfl_up(sv, d); if (tid >= d) sv += t; }
            wsum[tid] = sv;
        }
        __syncthreads();
        int excl = (wid ? wsum[wid - 1] : 0) + v - x;
        if (tid < NBKT) {
            pfx[tid] = excl;
            rbs[tid] = bptrr[tid] + Cr[(size_t)w * NBKT + tid] - excl;
            cnt[tid] = 0;
        }
        if (tid == 0) pfx[NBKT] = m;
    }
    __syncthreads();
    #pragma unroll
    for (int i = 0; i < 16; ++i) {
        int off = tid + i * 1024;
        if (off < m) {
            int b = rr[i] >> BSH;
            int l = atomicAdd(&cnt[b], 1);
            ustg[pfx[b] + l] = (wb[i] & ~127u) | ((unsigned)rr[i] & 127u);
        }
    }
    __syncthreads();
    for (int j = tid; j < m; j += 1024) {
        int lo = 0, hi = NBKT;
        while (hi - lo > 1) { int mid = (lo + hi) >> 1; if (pfx[mid] <= j) lo = mid; else hi = mid; }
        degp[(size_t)(rbs[lo] + j)] = ustg[j];
    }
}

__global__ __launch_bounds__(256) void deg_k(const unsigned* __restrict__ degp,
                                             const int* __restrict__ bptrr,
                                             float* __restrict__ dinv,
                                             float* __restrict__ q0, int N) {
    __shared__ float acc[128];
    int rb = blockIdx.x, tid = threadIdx.x;
    if (tid < 128) acc[tid] = 0.0f;
    __syncthreads();
    int s = bptrr[rb], e = bptrr[rb + 1];
    for (int i = s + tid; i < e; i += 256) {
        unsigned p = degp[i];
        atomicAdd(&acc[p & 127], __uint_as_float(p & ~127u));
    }
    __syncthreads();
    if (tid < 128) {
        int r = rb * 128 + tid;
        if (r < N) {
            float dv = 1.0f / fmaxf(acc[tid] + 1.0f, 1e-8f);
            dinv[r] = dv;
            q0[r] = dv;
        }
    }
}

__global__ __launch_bounds__(256) void dega_k(const int* __restrict__ ei,
                                              const float* __restrict__ ew,
                                              float* __restrict__ deg, int E) {
    int e = blockIdx.x * 256 + threadIdx.x;
    if (e < E) atomicAdd(&deg[ei[e]], ew[e]);
}

__global__ __launch_bounds__(256) void inv_k(const float* __restrict__ deg,
                                             float* __restrict__ dinv,
                                             float* __restrict__ q0, int N) {
    int i = blockIdx.x * 256 + threadIdx.x;
    if (i < N) {
        float dv = 1.0f / fmaxf(deg[i] + 1.0f, 1e-8f);
        dinv[i] = dv;
        q0[i] = dv;
    }
}

__global__ __launch_bounds__(256) void step_k(const uint2* __restrict__ csr,
                                              const int* __restrict__ bptrc,
                                              const float* __restrict__ q,
                                              const float* __restrict__ dinv,
                                              float* __restrict__ prob_out,
                                              float* __restrict__ q_out, int N) {
    __shared__ float acc[128];
    int cb = blockIdx.x, tid = threadIdx.x;
    if (tid < 128) acc[tid] = 0.0f;
    __syncthreads();
    int s = bptrc[cb], e = bptrc[cb + 1];
    int i = s + tid;
    for (; i + 768 < e; i += 1024) {
        uint2 t0 = csr[i], t1 = csr[i + 256], t2 = csr[i + 512], t3 = csr[i + 768];
        float v0 = q[t0.x & 0x1FFFFFF] * __uint_as_float(t0.y);
        float v1 = q[t1.x & 0x1FFFFFF] * __uint_as_float(t1.y);
        float v2 = q[t2.x & 0x1FFFFFF] * __uint_as_float(t2.y);
        float v3 = q[t3.x & 0x1FFFFFF] * __uint_as_float(t3.y);
        atomicAdd(&acc[t0.x >> 25], v0);
        atomicAdd(&acc[t1.x >> 25], v1);
        atomicAdd(&acc[t2.x >> 25], v2);
        atomicAdd(&acc[t3.x >> 25], v3);
    }
    for (; i < e; i += 256) {
        uint2 t = csr[i];
        atomicAdd(&acc[t.x >> 25], q[t.x & 0x1FFFFFF] * __uint_as_float(t.y));
    }
    __syncthreads();
    if (tid < 128) {
        int c = cb * 128 + tid;
        if (c < N) {
            float p = acc[tid] + q[c];
            prob_out[c] = p;
            q_out[c] = p * dinv[c];
        }
    }
}

__global__ __launch_bounds__(256) void init_push(float* __restrict__ probs, int N) {
    int i = blockIdx.x * 256 + threadIdx.x;
    if (i < N) {
        probs[i] = 1.0f;
        #pragma unroll
        for (int k = 1; k <= WALK; ++k) probs[(size_t)k * N + i] = 0.0f;
    }
}

__global__ __launch_bounds__(256) void step_push(const int* __restrict__ ei,
                                                 const float* __restrict__ ew,
                                                 const float* __restrict__ dinv,
                                                 const float* __restrict__ src,
                                                 float* __restrict__ dst,
                                                 int E, int N) {
    int idx = blockIdx.x * 256 + threadIdx.x;
    if (idx < E) {
        int r = ei[idx], c = ei[E + idx];
        atomicAdd(&dst[c], src[r] * ew[idx] * dinv[r]);
    } else if (idx < E + N) {
        int i = idx - E;
        atomicAdd(&dst[i], src[i] * dinv[i]);
    }
}

// ---------------- launch ----------------

extern "C" void kernel_launch(void* const* d_in, const int* in_sizes, int n_in,
                              void* d_out, int out_size, void* d_ws, size_t ws_size,
                              hipStream_t stream) {
    const int*   ei = (const int*)d_in[0];
    const float* ew = (const float*)d_in[2];
    const float* W1 = (const float*)d_in[3];
    const float* b1 = (const float*)d_in[4];
    const float* W2 = (const float*)d_in[5];
    const float* b2 = (const float*)d_in[6];
    const int E = in_sizes[2];
    const int N = out_size / HID;
    float* out = (float*)d_out;

    const int NB  = (N + 255) / 256;
    const int NBM = (N + 127) / 128;

    // ---- R7 fast path feasibility ----
    const int RBK = (N + 127) / 128;
    const int NB2 = (N + CB - 1) / CB;
    const int NW  = (E + CH1 - 1) / CH1;
    size_t partw = (size_t)NB2 * SLICES * CB;
    size_t need7 = ((size_t)4 * E + 19 * (size_t)N + (size_t)RBK * 2 + (size_t)NB2 * 2 + 64) * 4;
    bool ok7 = N <= 131072 && RBK <= MAXRB && NB2 <= MAXCB &&
               (size_t)NW * RBK <= (size_t)2 * E &&          // C1 fits csr region
               (size_t)NW * NB2 <= (size_t)16 * N &&         // C2 fits probs region
               partw <= (size_t)2 * E &&                     // part fits buf1 region
               ws_size >= need7;

    if (ok7) {
        char* p = (char*)d_ws;
        uint2* csr  = (uint2*)p;             p += (size_t)E * 8;
        uint2* buf1 = (uint2*)p;             p += (size_t)E * 8;
        int* bptr1  = (int*)p;               p += (size_t)(RBK + 1) * 4;
        int* tot1   = (int*)p;               p += (size_t)RBK * 4;
        int* bptr2  = (int*)p;               p += (size_t)(NB2 + 1) * 4;
        int* tot2   = (int*)p;               p += (size_t)NB2 * 4;
        float* dinv = (float*)p;             p += (size_t)N * 4;
        float* qA   = (float*)p;             p += (size_t)N * 4;
        float* qB   = (float*)p;             p += (size_t)N * 4;
        float* probs = (float*)p;
        int* C1 = (int*)csr;                 // overlay: dead before p2scat writes csr
        int* C2 = (int*)probs;               // overlay: dead before steps write probs
        float* part = (float*)buf1;          // overlay: buf1 dead after pass 2

        // pass 1: sort by row>>7
        p1hist_k<<<NW, 256, 0, stream>>>(ei, C1, RBK, E);
        colscan_k<<<(RBK + 255) / 256, 256, 0, stream>>>(C1, tot1, RBK, NW);
        bktscan_k<<<1, 1024, 0, stream>>>(tot1, bptr1, RBK, E);
        p1scat_k<<<NW, 1024, 0, stream>>>(ei, ew, C1, bptr1, buf1, RBK, E);
        deg2_k<<<RBK, 256, 0, stream>>>(buf1, bptr1, dinv, qA, N);
        // pass 2: stable sort by col>>11
        p2hist_k<<<NW, 256, 0, stream>>>(buf1, C2, NB2, E);
        colscan_k<<<1, 256, 0, stream>>>(C2, tot2, NB2, NW);
        bktscan_k<<<1, 1024, 0, stream>>>(tot2, bptr2, NB2, E);
        p2scat_k<<<NW, 1024, 0, stream>>>(buf1, C2, bptr2, csr, NB2, E);
        // 16 steps
        float* qs = qA; float* qd = qB;
        for (int k = 0; k < WALK; ++k) {
            step2_k<<<NB2 * SLICES, 256, 0, stream>>>(csr, bptr2, qs, part);
            reduce_k<<<NB, 256, 0, stream>>>(part, qs, dinv,
                                             probs + (size_t)k * N, qd, N);
            float* t = qs; qs = qd; qd = t;
        }
        mlp2_kernel<<<NBM, 128, 0, stream>>>(probs, W1, b1, W2, b2, out, N);
        return;
    }

    // ---- R6 fallback ----
    const int NBKT = (N + 127) / 128;
    const int NWF  = (E + CHUNK - 1) / CHUNK;
    size_t wordsB = (size_t)2 * E + 2 * (size_t)NBKT + 1 + 19 * (size_t)N + 64;
    size_t wordsA = wordsB + (size_t)E + 2 * (size_t)NBKT + 1;
    bool overlay_ok = (size_t)2 * NWF * NBKT <= (size_t)16 * N;
    bool okA = NBKT <= MAXB && overlay_ok && ws_size >= wordsA * 4;
    bool okB = NBKT <= MAXB && ((size_t)NWF * NBKT <= (size_t)16 * N) && ws_size >= wordsB * 4;

    if (okA || okB) {
        char* p = (char*)d_ws;
        uint2* csr = (uint2*)p;              p += (size_t)E * 8;
        unsigned* degp = nullptr;
        if (okA) { degp = (unsigned*)p;      p += (size_t)E * 4; }
        int* bptrc = (int*)p;                p += (size_t)(NBKT + 1) * 4;
        int* totc  = (int*)p;                p += (size_t)NBKT * 4;
        int* bptrr = nullptr; int* totr = nullptr;
        if (okA) {
            bptrr = (int*)p;                 p += (size_t)(NBKT + 1) * 4;
            totr  = (int*)p;                 p += (size_t)NBKT * 4;
        }
        float* dinv = (float*)p;             p += (size_t)N * 4;
        float* qA   = (float*)p;             p += (size_t)N * 4;
        float* qB   = (float*)p;             p += (size_t)N * 4;
        float* probs = (float*)p;
        int* Cc = (int*)probs;
        int* Cr = Cc + (size_t)NWF * NBKT;

        hist_k<<<NWF, 256, 0, stream>>>(ei, Cc, Cr, NBKT, E, okA ? 1 : 0);
        colscan_k<<<(NBKT + 255) / 256, 256, 0, stream>>>(Cc, totc, NBKT, NWF);
        bktscan_k<<<1, 1024, 0, stream>>>(totc, bptrc, NBKT, E);
        if (okA) {
            colscan_k<<<(NBKT + 255) / 256, 256, 0, stream>>>(Cr, totr, NBKT, NWF);
            bktscan_k<<<1, 1024, 0, stream>>>(totr, bptrr, NBKT, E);
        }
        scatter_sort_k<<<NWF, 1024, 0, stream>>>(ei, ew, Cc, Cr, bptrc, bptrr,
                                                 csr, degp, NBKT, E, okA ? 1 : 0);
        if (okA) {
            deg_k<<<NBKT, 256, 0, stream>>>(degp, bptrr, dinv, qA, N);
        } else {
            hipMemsetAsync(qB, 0, (size_t)N * 4, stream);
            dega_k<<<(E + 255) / 256, 256, 0, stream>>>(ei, ew, qB, E);
            inv_k<<<NB, 256, 0, stream>>>(qB, dinv, qA, N);
        }
        float* qs = qA; float* qd = qB;
        for (int k = 0; k < WALK; ++k) {
            step_k<<<NBKT, 256, 0, stream>>>(csr, bptrc, qs, dinv,
                                             probs + (size_t)k * N, qd, N);
            float* t = qs; qs = qd; qd = t;
        }
        mlp2_kernel<<<NBM, 128, 0, stream>>>(probs, W1, b1, W2, b2, out, N);
    } else {
        float* deg   = (float*)d_ws;
        float* dinv  = deg + N;
        float* probs = dinv + N;
        hipMemsetAsync(deg, 0, (size_t)N * 4, stream);
        init_push<<<NB, 256, 0, stream>>>(probs, N);
        dega_k<<<(E + 255) / 256, 256, 0, stream>>>(ei, ew, deg, E);
        inv_k<<<NB, 256, 0, stream>>>(deg, dinv, dinv, N);
        for (int k = 0; k < WALK; ++k) {
            step_push<<<(E + N + 255) / 256, 256, 0, stream>>>(
                ei, ew, dinv, probs + (size_t)k * N, probs + (size_t)(k + 1) * N, E, N);
        }
        mlp2_kernel<<<NBM, 128, 0, stream>>>(probs + N, W1, b1, W2, b2, out, N);
    }
}

// Round 8
// 980.437 us; speedup vs baseline: 1.3423x; 1.3423x over previous
//
#include <hip/hip_runtime.h>

#define WALK 16
#define HID 64

// ---------------- fast path params ----------------
#define CH1 8192       // sort chunk (edges)
#define RBSH 7         // pass-1 key: row block = 128 rows
#define CBSH 11        // pass-2 key: col bucket = 2048 cols
#define CB 2048
#define SLICES 20      // step parallel slices per col bucket
#define MAXRB 1024     // RBK <= 1024  (N <= 131072)
#define MAXCB 64       // NB2 <= 64

// ---------------- R6 fallback params ----------------
#define CHUNK 16384
#define BSH 7
#define MAXB 808

// ===========================================================================
// R7: edges sorted by (col_bucket[2048], row_block[128]) via two counting-sort
// passes -> step gathers hit ~8 cache lines/wave instead of 64. R8: the
// per-bucket-over-chunks scan (colscan) was serial per thread (782 threads x
// 782 iters, 187us x2 = 28% of runtime, occupancy 0.15%); now one block per
// bucket with a parallel 256-wide tile scan (colscan2_k).
//
// Packing (intermediate buf1): lo = row | (col&0x7FFF)<<17 ; hi = (w&~3)|(col>>15)
// Packing (final csr):         lo = row | (col&2047)<<17   ; hi = w&~3
//
// ws (words): [csr 2E | buf1 2E | bptr1 RBK+1 | tot1 RBK | bptr2 NB2+1 |
//              tot2 NB2 | dinv N | qA N | qB N | probs 16N]
// overlays: C1 (NW*RBK) in csr region; C2 (NW*NB2) in probs;
//           part (NB2*SLICES*2048) in buf1 (dead after pass 2).
// ===========================================================================

// ---- R8: parallel per-bucket scan over chunks: one block per bucket ----
__global__ __launch_bounds__(256) void colscan2_k(int* __restrict__ C,
                                                  int* __restrict__ tot,
                                                  int NBKT, int NW) {
    __shared__ int wsum[4];
    __shared__ int wexcl[4];
    __shared__ int btot;
    __shared__ int carry_s;
    int b = blockIdx.x, tid = threadIdx.x, lane = tid & 63, wid = tid >> 6;
    if (tid == 0) carry_s = 0;
    __syncthreads();
    for (int base = 0; base < NW; base += 256) {
        int w = base + tid;
        int x = (w < NW) ? C[(size_t)w * NBKT + b] : 0;
        int v = x;
        #pragma unroll
        for (int d = 1; d < 64; d <<= 1) { int t = __shfl_up(v, d); if (lane >= d) v += t; }
        if (lane == 63) wsum[wid] = v;
        __syncthreads();
        if (tid == 0) {
            int s = 0;
            #pragma unroll
            for (int i = 0; i < 4; ++i) { int t = wsum[i]; wexcl[i] = s; s += t; }
            btot = s;
        }
        __syncthreads();
        int excl = carry_s + wexcl[wid] + v - x;
        if (w < NW) C[(size_t)w * NBKT + b] = excl;
        __syncthreads();
        if (tid == 0) carry_s += btot;
        __syncthreads();
    }
    if (tid == 0) tot[b] = carry_s;
}

__global__ __launch_bounds__(1024) void bktscan_k(const int* __restrict__ tot,
                                                  int* __restrict__ ptr,
                                                  int NBKT, int E) {
    __shared__ int wsum[16];
    __shared__ int carry_s;
    int tid = threadIdx.x, lane = tid & 63, wid = tid >> 6;
    if (tid == 0) carry_s = 0;
    __syncthreads();
    for (int base = 0; base < NBKT; base += 1024) {
        int x = (base + tid < NBKT) ? tot[base + tid] : 0;
        int v = x;
        #pragma unroll
        for (int d = 1; d < 64; d <<= 1) { int t = __shfl_up(v, d); if (lane >= d) v += t; }
        __syncthreads();
        if (lane == 63) wsum[wid] = v;
        __syncthreads();
        if (tid < 16) {
            int sv = wsum[tid];
            #pragma unroll
            for (int d = 1; d < 16; d <<= 1) { int t = __shfl_up(sv, d); if (tid >= d) sv += t; }
            wsum[tid] = sv;
        }
        __syncthreads();
        int woff = wid ? wsum[wid - 1] : 0;
        int carry = carry_s;
        if (base + tid < NBKT) ptr[base + tid] = carry + woff + v - x;
        __syncthreads();
        if (tid == 0) carry_s = carry + wsum[15];
    }
    if (tid == 0) ptr[NBKT] = E;
}

// ---------------- pass 1: sort by row>>7 ----------------

__global__ __launch_bounds__(256) void p1hist_k(const int* __restrict__ ei,
                                                int* __restrict__ C1,
                                                int RBK, int E) {
    __shared__ int cnt[MAXRB];
    int w = blockIdx.x, tid = threadIdx.x;
    for (int b = tid; b < RBK; b += 256) cnt[b] = 0;
    __syncthreads();
    int s = w * CH1, m = min(E - s, CH1);
    int vec = m & ~3;
    for (int off = 4 * tid; off < vec; off += 1024) {
        int4 r4 = *(const int4*)(ei + s + off);
        atomicAdd(&cnt[r4.x >> RBSH], 1);
        atomicAdd(&cnt[r4.y >> RBSH], 1);
        atomicAdd(&cnt[r4.z >> RBSH], 1);
        atomicAdd(&cnt[r4.w >> RBSH], 1);
    }
    for (int off = vec + tid; off < m; off += 256)
        atomicAdd(&cnt[ei[s + off] >> RBSH], 1);
    __syncthreads();
    for (int b = tid; b < RBK; b += 256) C1[(size_t)w * RBK + b] = cnt[b];
}

__global__ __launch_bounds__(1024) void p1scat_k(const int* __restrict__ ei,
                                                 const float* __restrict__ ew,
                                                 const int* __restrict__ C1,
                                                 const int* __restrict__ bptr1,
                                                 uint2* __restrict__ buf1,
                                                 int RBK, int E) {
    __shared__ uint2 stg[CH1];                 // 64 KB
    __shared__ int cnt[MAXRB];
    __shared__ int pfx[MAXRB + 1];
    __shared__ int rbs[MAXRB];
    __shared__ int wsum[16];
    int w = blockIdx.x, tid = threadIdx.x, lane = tid & 63, wid = tid >> 6;
    int s = w * CH1, m = min(E - s, CH1);

    int rr[8]; unsigned cc[8], wb[8];
    for (int b = tid; b < RBK; b += 1024) cnt[b] = 0;
    __syncthreads();
    #pragma unroll
    for (int i = 0; i < 8; ++i) {
        int off = tid + i * 1024;
        bool ok = off < m;
        int r = 0, c = 0; float v = 0.0f;
        if (ok) { r = ei[s + off]; c = ei[E + s + off]; v = ew[s + off]; }
        rr[i] = r; cc[i] = (unsigned)c; wb[i] = __float_as_uint(v);
        if (ok) atomicAdd(&cnt[r >> RBSH], 1);
    }
    __syncthreads();
    {   // block scan over RBK (<=1024) buckets
        int x = (tid < RBK) ? cnt[tid] : 0;
        int v = x;
        #pragma unroll
        for (int d = 1; d < 64; d <<= 1) { int t = __shfl_up(v, d); if (lane >= d) v += t; }
        if (lane == 63) wsum[wid] = v;
        __syncthreads();
        if (tid < 16) {
            int sv = wsum[tid];
            #pragma unroll
            for (int d = 1; d < 16; d <<= 1) { int t = __shfl_up(sv, d); if (tid >= d) sv += t; }
            wsum[tid] = sv;
        }
        __syncthreads();
        int excl = (wid ? wsum[wid - 1] : 0) + v - x;
        if (tid < RBK) {
            pfx[tid] = excl;
            rbs[tid] = bptr1[tid] + C1[(size_t)w * RBK + tid] - excl;
            cnt[tid] = 0;
        }
        if (tid == 0) pfx[RBK] = m;
    }
    __syncthreads();
    #pragma unroll
    for (int i = 0; i < 8; ++i) {
        int off = tid + i * 1024;
        if (off < m) {
            int b = rr[i] >> RBSH;
            int l = atomicAdd(&cnt[b], 1);
            stg[pfx[b] + l] = make_uint2((unsigned)rr[i] | ((cc[i] & 0x7FFFu) << 17),
                                         (wb[i] & ~3u) | (cc[i] >> 15));
        }
    }
    __syncthreads();
    for (int j = tid; j < m; j += 1024) {
        int lo = 0, hi = RBK;
        while (hi - lo > 1) { int mid = (lo + hi) >> 1; if (pfx[mid] <= j) lo = mid; else hi = mid; }
        buf1[(size_t)(rbs[lo] + j)] = stg[j];
    }
}

// ---- deg from row-sorted buf1: coalesced stream + 128-slot LDS acc ----
__global__ __launch_bounds__(256) void deg2_k(const uint2* __restrict__ buf1,
                                              const int* __restrict__ bptr1,
                                              float* __restrict__ dinv,
                                              float* __restrict__ q0, int N) {
    __shared__ float acc[128];
    int rb = blockIdx.x, tid = threadIdx.x;
    if (tid < 128) acc[tid] = 0.0f;
    __syncthreads();
    int s = bptr1[rb], e = bptr1[rb + 1];
    for (int i = s + tid; i < e; i += 256) {
        uint2 t = buf1[i];
        atomicAdd(&acc[t.x & 127], __uint_as_float(t.y & ~3u));
    }
    __syncthreads();
    if (tid < 128) {
        int r = rb * 128 + tid;
        if (r < N) {
            float dv = 1.0f / fmaxf(acc[tid] + 1.0f, 1e-8f);   // +1 self-loop
            dinv[r] = dv;
            q0[r] = dv;                                        // prob0 = 1
        }
    }
}

// ---------------- pass 2: stable sort by col>>11 ----------------

__global__ __launch_bounds__(256) void p2hist_k(const uint2* __restrict__ buf1,
                                                int* __restrict__ C2,
                                                int NB2, int E) {
    __shared__ int cnt[MAXCB];
    int w = blockIdx.x, tid = threadIdx.x;
    if (tid < MAXCB) cnt[tid] = 0;
    __syncthreads();
    int s = w * CH1, m = min(E - s, CH1);
    for (int off = tid; off < m; off += 256) {
        uint2 t = buf1[s + off];
        unsigned col = (t.x >> 17) | ((t.y & 3u) << 15);
        atomicAdd(&cnt[col >> CBSH], 1);
    }
    __syncthreads();
    if (tid < NB2) C2[(size_t)w * NB2 + tid] = cnt[tid];
}

__global__ __launch_bounds__(1024) void p2scat_k(const uint2* __restrict__ buf1,
                                                 const int* __restrict__ C2,
                                                 const int* __restrict__ bptr2,
                                                 uint2* __restrict__ csr,
                                                 int NB2, int E) {
    __shared__ uint2 stg[CH1];
    __shared__ int cnt[MAXCB];
    __shared__ int pfx[MAXCB + 1];
    __shared__ int rbs[MAXCB];
    int w = blockIdx.x, tid = threadIdx.x;
    int s = w * CH1, m = min(E - s, CH1);

    uint2 tt[8]; int bb[8];
    if (tid < MAXCB) cnt[tid] = 0;
    __syncthreads();
    #pragma unroll
    for (int i = 0; i < 8; ++i) {
        int off = tid + i * 1024;
        uint2 t = make_uint2(0, 0);
        int b = 0;
        if (off < m) {
            t = buf1[s + off];
            unsigned col = (t.x >> 17) | ((t.y & 3u) << 15);
            b = (int)(col >> CBSH);
            atomicAdd(&cnt[b], 1);
        }
        tt[i] = t; bb[i] = b;
    }
    __syncthreads();
    if (tid < 64) {   // wave-0 scan over 64 bucket slots
        int x = cnt[tid];
        int v = x;
        #pragma unroll
        for (int d = 1; d < 64; d <<= 1) { int t = __shfl_up(v, d); if (tid >= d) v += t; }
        pfx[tid] = v - x;
        if (tid < NB2) rbs[tid] = bptr2[tid] + C2[(size_t)w * NB2 + tid] - (v - x);
        cnt[tid] = 0;
        if (tid == 63) pfx[64] = v;
    }
    __syncthreads();
    #pragma unroll
    for (int i = 0; i < 8; ++i) {
        int off = tid + i * 1024;
        if (off < m) {
            int b = bb[i];
            int l = atomicAdd(&cnt[b], 1);
            unsigned col = (tt[i].x >> 17) | ((tt[i].y & 3u) << 15);
            unsigned row = tt[i].x & 0x1FFFFu;
            stg[pfx[b] + l] = make_uint2(row | ((col & 2047u) << 17), tt[i].y & ~3u);
        }
    }
    __syncthreads();
    for (int j = tid; j < m; j += 1024) {
        int lo = 0, hi = MAXCB;
        while (hi - lo > 1) { int mid = (lo + hi) >> 1; if (pfx[mid] <= j) lo = mid; else hi = mid; }
        csr[(size_t)(rbs[lo] + j)] = stg[j];
    }
}

// ---------------- steps: sliced bucket accumulate + reduce ----------------

__global__ __launch_bounds__(256) void step2_k(const uint2* __restrict__ csr,
                                               const int* __restrict__ bptr2,
                                               const float* __restrict__ q,
                                               float* __restrict__ part) {
    __shared__ float acc[CB];
    int blk = blockIdx.x;
    int b = blk / SLICES, sl = blk % SLICES;
    int tid = threadIdx.x;
    for (int t = tid; t < CB; t += 256) acc[t] = 0.0f;
    __syncthreads();
    int be = bptr2[b], en = bptr2[b + 1], len = en - be;
    int i0 = be + (int)((long long)len * sl / SLICES);
    int i1 = be + (int)((long long)len * (sl + 1) / SLICES);
    int i = i0 + tid;
    for (; i + 768 < i1; i += 1024) {
        uint2 t0 = csr[i], t1 = csr[i + 256], t2 = csr[i + 512], t3 = csr[i + 768];
        float v0 = q[t0.x & 0x1FFFF] * __uint_as_float(t0.y);
        float v1 = q[t1.x & 0x1FFFF] * __uint_as_float(t1.y);
        float v2 = q[t2.x & 0x1FFFF] * __uint_as_float(t2.y);
        float v3 = q[t3.x & 0x1FFFF] * __uint_as_float(t3.y);
        atomicAdd(&acc[t0.x >> 17], v0);
        atomicAdd(&acc[t1.x >> 17], v1);
        atomicAdd(&acc[t2.x >> 17], v2);
        atomicAdd(&acc[t3.x >> 17], v3);
    }
    for (; i < i1; i += 256) {
        uint2 t = csr[i];
        atomicAdd(&acc[t.x >> 17], q[t.x & 0x1FFFF] * __uint_as_float(t.y));
    }
    __syncthreads();
    float* dst = part + (size_t)blk * CB;
    for (int t = tid; t < CB; t += 256) dst[t] = acc[t];
}

__global__ __launch_bounds__(256) void reduce_k(const float* __restrict__ part,
                                                const float* __restrict__ q,
                                                const float* __restrict__ dinv,
                                                float* __restrict__ prob_out,
                                                float* __restrict__ q_out, int N) {
    int c = blockIdx.x * 256 + threadIdx.x;
    if (c >= N) return;
    int b = c >> CBSH, off = c & (CB - 1);
    const float* p = part + (size_t)b * SLICES * CB + off;
    float sum = 0.0f;
    #pragma unroll
    for (int s = 0; s < SLICES; ++s) sum += p[(size_t)s * CB];
    float pr = sum + q[c];          // self-loop: prob[c]*dinv[c] = q[c]
    prob_out[c] = pr;
    q_out[c] = pr * dinv[c];
}

// ---------------- MLP (uniform weight loads, R6-proven) ----------------

__global__ __launch_bounds__(128) void mlp2_kernel(const float* __restrict__ probs,
                                                   const float* __restrict__ W1,
                                                   const float* __restrict__ b1,
                                                   const float* __restrict__ W2,
                                                   const float* __restrict__ b2,
                                                   float* __restrict__ out, int N) {
    int n = blockIdx.x * 128 + threadIdx.x;
    if (n >= N) return;
    float p[WALK];
    #pragma unroll
    for (int k = 0; k < WALK; ++k) p[k] = probs[(size_t)k * N + n];
    float h[HID];
    #pragma unroll
    for (int j = 0; j < HID; ++j) {
        float a = b1[j];
        #pragma unroll
        for (int k = 0; k < WALK; ++k) a += W1[j * WALK + k] * p[k];
        h[j] = fmaxf(a, 0.0f);
    }
    #pragma unroll
    for (int j = 0; j < HID; j += 4) {
        float4 o;
        float* op = (float*)&o;
        #pragma unroll
        for (int qq = 0; qq < 4; ++qq) {
            float a = b2[j + qq];
            #pragma unroll
            for (int k = 0; k < HID; ++k) a += W2[(j + qq) * HID + k] * h[k];
            op[qq] = a;
        }
        *(float4*)&out[(size_t)n * HID + j] = o;
    }
}

// ===========================================================================
// R6 fallback path — used when ws too small for the fast path.
// ===========================================================================

__global__ __launch_bounds__(256) void hist_k(const int* __restrict__ ei,
                                              int* __restrict__ Cc,
                                              int* __restrict__ Cr,
                                              int NBKT, int E, int do_row) {
    __shared__ int cntc[MAXB];
    __shared__ int cntr[MAXB];
    int w = blockIdx.x, tid = threadIdx.x;
    for (int b = tid; b < NBKT; b += 256) { cntc[b] = 0; cntr[b] = 0; }
    __syncthreads();
    int s = w * CHUNK;
    int cnt = min(E - s, CHUNK);
    const int* colp = ei + E;
    int vec = ((E & 3) == 0) ? (cnt & ~3) : 0;
    for (int off = 4 * tid; off < vec; off += 1024) {
        int4 c4 = *(const int4*)(colp + s + off);
        atomicAdd(&cntc[c4.x >> BSH], 1);
        atomicAdd(&cntc[c4.y >> BSH], 1);
        atomicAdd(&cntc[c4.z >> BSH], 1);
        atomicAdd(&cntc[c4.w >> BSH], 1);
        if (do_row) {
            int4 r4 = *(const int4*)(ei + s + off);
            atomicAdd(&cntr[r4.x >> BSH], 1);
            atomicAdd(&cntr[r4.y >> BSH], 1);
            atomicAdd(&cntr[r4.z >> BSH], 1);
            atomicAdd(&cntr[r4.w >> BSH], 1);
        }
    }
    for (int off = vec + tid; off < cnt; off += 256) {
        atomicAdd(&cntc[colp[s + off] >> BSH], 1);
        if (do_row) atomicAdd(&cntr[ei[s + off] >> BSH], 1);
    }
    __syncthreads();
    for (int b = tid; b < NBKT; b += 256) {
        Cc[(size_t)w * NBKT + b] = cntc[b];
        if (do_row) Cr[(size_t)w * NBKT + b] = cntr[b];
    }
}

__global__ __launch_bounds__(1024) void scatter_sort_k(const int* __restrict__ ei,
                                                       const float* __restrict__ ew,
                                                       const int* __restrict__ Cc,
                                                       const int* __restrict__ Cr,
                                                       const int* __restrict__ bptrc,
                                                       const int* __restrict__ bptrr,
                                                       uint2* __restrict__ csr,
                                                       unsigned* __restrict__ degp,
                                                       int NBKT, int E, int do_row) {
    __shared__ uint2 stg[CHUNK];
    __shared__ int cnt[MAXB];
    __shared__ int pfx[MAXB + 1];
    __shared__ int rbs[MAXB];
    __shared__ int wsum[16];
    unsigned* ustg = (unsigned*)stg;
    const int w = blockIdx.x, tid = threadIdx.x;
    const int lane = tid & 63, wid = tid >> 6;
    const int s = w * CHUNK;
    const int m = min(E - s, CHUNK);

    int rr[16], cc[16];
    unsigned wb[16];
    for (int b = tid; b < NBKT; b += 1024) cnt[b] = 0;
    __syncthreads();
    #pragma unroll
    for (int i = 0; i < 16; ++i) {
        int off = tid + i * 1024;
        bool ok = off < m;
        int r = 0, c = 0; float v = 0.0f;
        if (ok) { r = ei[s + off]; c = ei[E + s + off]; v = ew[s + off]; }
        rr[i] = r; cc[i] = c; wb[i] = __float_as_uint(v);
        if (ok) atomicAdd(&cnt[c >> BSH], 1);
    }
    __syncthreads();
    {
        int x = (tid < NBKT) ? cnt[tid] : 0;
        int v = x;
        #pragma unroll
        for (int d = 1; d < 64; d <<= 1) { int t = __shfl_up(v, d); if (lane >= d) v += t; }
        if (lane == 63) wsum[wid] = v;
        __syncthreads();
        if (tid < 16) {
            int sv = wsum[tid];
            #pragma unroll
            for (int d = 1; d < 16; d <<= 1) { int t = __shfl_up(sv, d); if (tid >= d) sv += t; }
            wsum[tid] = sv;
        }
        __syncthreads();
        int excl = (wid ? wsum[wid - 1] : 0) + v - x;
        if (tid < NBKT) {
            pfx[tid] = excl;
            rbs[tid] = bptrc[tid] + Cc[(size_t)w * NBKT + tid] - excl;
            cnt[tid] = 0;
        }
        if (tid == 0) pfx[NBKT] = m;
    }
    __syncthreads();
    #pragma unroll
    for (int i = 0; i < 16; ++i) {
        int off = tid + i * 1024;
        if (off < m) {
            int b = cc[i] >> BSH;
            int l = atomicAdd(&cnt[b], 1);
            stg[pfx[b] + l] = make_uint2((unsigned)rr[i] | ((unsigned)(cc[i] & 127) << 25), wb[i]);
        }
    }
    __syncthreads();
    for (int j = tid; j < m; j += 1024) {
        int lo = 0, hi = NBKT;
        while (hi - lo > 1) { int mid = (lo + hi) >> 1; if (pfx[mid] <= j) lo = mid; else hi = mid; }
        csr[(size_t)(rbs[lo] + j)] = stg[j];
    }
    if (!do_row) return;
    __syncthreads();
    for (int b = tid; b < NBKT; b += 1024) cnt[b] = 0;
    __syncthreads();
    #pragma unroll
    for (int i = 0; i < 16; ++i) {
        int off = tid + i * 1024;
        if (off < m) atomicAdd(&cnt[rr[i] >> BSH], 1);
    }
    __syncthreads();
    {
        int x = (tid < NBKT) ? cnt[tid] : 0;
        int v = x;
        #pragma unroll
        for (int d = 1; d < 64; d <<= 1) { int t = __shfl_up(v, d); if (lane >= d) v += t; }
        if (lane == 63) wsum[wid] = v;
        __syncthreads();
        if (tid < 16) {
            int sv = wsum[tid];
            #pragma unroll
            for (int d = 1; d < 16; d <<= 1) { int t = __shfl_up(sv, d); if (tid >= d) sv += t; }
            wsum[tid] = sv;
        }
        __syncthreads();
        int excl = (wid ? wsum[wid - 1] : 0) + v - x;
        if (tid < NBKT) {
            pfx[tid] = excl;
            rbs[tid] = bptrr[tid] + Cr[(size_t)w * NBKT + tid] - excl;
            cnt[tid] = 0;
        }
        if (tid == 0) pfx[NBKT] = m;
    }
    __syncthreads();
    #pragma unroll
    for (int i = 0; i < 16; ++i) {
        int off = tid + i * 1024;
        if (off < m) {
            int b = rr[i] >> BSH;
            int l = atomicAdd(&cnt[b], 1);
            ustg[pfx[b] + l] = (wb[i] & ~127u) | ((unsigned)rr[i] & 127u);
        }
    }
    __syncthreads();
    for (int j = tid; j < m; j += 1024) {
        int lo = 0, hi = NBKT;
        while (hi - lo > 1) { int mid = (lo + hi) >> 1; if (pfx[mid] <= j) lo = mid; else hi = mid; }
        degp[(size_t)(rbs[lo] + j)] = ustg[j];
    }
}

__global__ __launch_bounds__(256) void deg_k(const unsigned* __restrict__ degp,
                                             const int* __restrict__ bptrr,
                                             float* __restrict__ dinv,
                                             float* __restrict__ q0, int N) {
    __shared__ float acc[128];
    int rb = blockIdx.x, tid = threadIdx.x;
    if (tid < 128) acc[tid] = 0.0f;
    __syncthreads();
    int s = bptrr[rb], e = bptrr[rb + 1];
    for (int i = s + tid; i < e; i += 256) {
        unsigned p = degp[i];
        atomicAdd(&acc[p & 127], __uint_as_float(p & ~127u));
    }
    __syncthreads();
    if (tid < 128) {
        int r = rb * 128 + tid;
        if (r < N) {
            float dv = 1.0f / fmaxf(acc[tid] + 1.0f, 1e-8f);
            dinv[r] = dv;
            q0[r] = dv;
        }
    }
}

__global__ __launch_bounds__(256) void dega_k(const int* __restrict__ ei,
                                              const float* __restrict__ ew,
                                              float* __restrict__ deg, int E) {
    int e = blockIdx.x * 256 + threadIdx.x;
    if (e < E) atomicAdd(&deg[ei[e]], ew[e]);
}

__global__ __launch_bounds__(256) void inv_k(const float* __restrict__ deg,
                                             float* __restrict__ dinv,
                                             float* __restrict__ q0, int N) {
    int i = blockIdx.x * 256 + threadIdx.x;
    if (i < N) {
        float dv = 1.0f / fmaxf(deg[i] + 1.0f, 1e-8f);
        dinv[i] = dv;
        q0[i] = dv;
    }
}

__global__ __launch_bounds__(256) void step_k(const uint2* __restrict__ csr,
                                              const int* __restrict__ bptrc,
                                              const float* __restrict__ q,
                                              const float* __restrict__ dinv,
                                              float* __restrict__ prob_out,
                                              float* __restrict__ q_out, int N) {
    __shared__ float acc[128];
    int cb = blockIdx.x, tid = threadIdx.x;
    if (tid < 128) acc[tid] = 0.0f;
    __syncthreads();
    int s = bptrc[cb], e = bptrc[cb + 1];
    int i = s + tid;
    for (; i + 768 < e; i += 1024) {
        uint2 t0 = csr[i], t1 = csr[i + 256], t2 = csr[i + 512], t3 = csr[i + 768];
        float v0 = q[t0.x & 0x1FFFFFF] * __uint_as_float(t0.y);
        float v1 = q[t1.x & 0x1FFFFFF] * __uint_as_float(t1.y);
        float v2 = q[t2.x & 0x1FFFFFF] * __uint_as_float(t2.y);
        float v3 = q[t3.x & 0x1FFFFFF] * __uint_as_float(t3.y);
        atomicAdd(&acc[t0.x >> 25], v0);
        atomicAdd(&acc[t1.x >> 25], v1);
        atomicAdd(&acc[t2.x >> 25], v2);
        atomicAdd(&acc[t3.x >> 25], v3);
    }
    for (; i < e; i += 256) {
        uint2 t = csr[i];
        atomicAdd(&acc[t.x >> 25], q[t.x & 0x1FFFFFF] * __uint_as_float(t.y));
    }
    __syncthreads();
    if (tid < 128) {
        int c = cb * 128 + tid;
        if (c < N) {
            float p = acc[tid] + q[c];
            prob_out[c] = p;
            q_out[c] = p * dinv[c];
        }
    }
}

__global__ __launch_bounds__(256) void init_push(float* __restrict__ probs, int N) {
    int i = blockIdx.x * 256 + threadIdx.x;
    if (i < N) {
        probs[i] = 1.0f;
        #pragma unroll
        for (int k = 1; k <= WALK; ++k) probs[(size_t)k * N + i] = 0.0f;
    }
}

__global__ __launch_bounds__(256) void step_push(const int* __restrict__ ei,
                                                 const float* __restrict__ ew,
                                                 const float* __restrict__ dinv,
                                                 const float* __restrict__ src,
                                                 float* __restrict__ dst,
                                                 int E, int N) {
    int idx = blockIdx.x * 256 + threadIdx.x;
    if (idx < E) {
        int r = ei[idx], c = ei[E + idx];
        atomicAdd(&dst[c], src[r] * ew[idx] * dinv[r]);
    } else if (idx < E + N) {
        int i = idx - E;
        atomicAdd(&dst[i], src[i] * dinv[i]);
    }
}

// ---------------- launch ----------------

extern "C" void kernel_launch(void* const* d_in, const int* in_sizes, int n_in,
                              void* d_out, int out_size, void* d_ws, size_t ws_size,
                              hipStream_t stream) {
    const int*   ei = (const int*)d_in[0];
    const float* ew = (const float*)d_in[2];
    const float* W1 = (const float*)d_in[3];
    const float* b1 = (const float*)d_in[4];
    const float* W2 = (const float*)d_in[5];
    const float* b2 = (const float*)d_in[6];
    const int E = in_sizes[2];
    const int N = out_size / HID;
    float* out = (float*)d_out;

    const int NB  = (N + 255) / 256;
    const int NBM = (N + 127) / 128;

    // ---- fast path feasibility ----
    const int RBK = (N + 127) / 128;
    const int NB2 = (N + CB - 1) / CB;
    const int NW  = (E + CH1 - 1) / CH1;
    size_t partw = (size_t)NB2 * SLICES * CB;
    size_t need7 = ((size_t)4 * E + 19 * (size_t)N + (size_t)RBK * 2 + (size_t)NB2 * 2 + 64) * 4;
    bool ok7 = N <= 131072 && RBK <= MAXRB && NB2 <= MAXCB &&
               (size_t)NW * RBK <= (size_t)2 * E &&
               (size_t)NW * NB2 <= (size_t)16 * N &&
               partw <= (size_t)2 * E &&
               ws_size >= need7;

    if (ok7) {
        char* p = (char*)d_ws;
        uint2* csr  = (uint2*)p;             p += (size_t)E * 8;
        uint2* buf1 = (uint2*)p;             p += (size_t)E * 8;
        int* bptr1  = (int*)p;               p += (size_t)(RBK + 1) * 4;
        int* tot1   = (int*)p;               p += (size_t)RBK * 4;
        int* bptr2  = (int*)p;               p += (size_t)(NB2 + 1) * 4;
        int* tot2   = (int*)p;               p += (size_t)NB2 * 4;
        float* dinv = (float*)p;             p += (size_t)N * 4;
        float* qA   = (float*)p;             p += (size_t)N * 4;
        float* qB   = (float*)p;             p += (size_t)N * 4;
        float* probs = (float*)p;
        int* C1 = (int*)csr;                 // overlay: dead before p2scat writes csr
        int* C2 = (int*)probs;               // overlay: dead before steps write probs
        float* part = (float*)buf1;          // overlay: buf1 dead after pass 2

        // pass 1: sort by row>>7
        p1hist_k<<<NW, 256, 0, stream>>>(ei, C1, RBK, E);
        colscan2_k<<<RBK, 256, 0, stream>>>(C1, tot1, RBK, NW);
        bktscan_k<<<1, 1024, 0, stream>>>(tot1, bptr1, RBK, E);
        p1scat_k<<<NW, 1024, 0, stream>>>(ei, ew, C1, bptr1, buf1, RBK, E);
        deg2_k<<<RBK, 256, 0, stream>>>(buf1, bptr1, dinv, qA, N);
        // pass 2: stable sort by col>>11
        p2hist_k<<<NW, 256, 0, stream>>>(buf1, C2, NB2, E);
        colscan2_k<<<NB2, 256, 0, stream>>>(C2, tot2, NB2, NW);
        bktscan_k<<<1, 1024, 0, stream>>>(tot2, bptr2, NB2, E);
        p2scat_k<<<NW, 1024, 0, stream>>>(buf1, C2, bptr2, csr, NB2, E);
        // 16 steps
        float* qs = qA; float* qd = qB;
        for (int k = 0; k < WALK; ++k) {
            step2_k<<<NB2 * SLICES, 256, 0, stream>>>(csr, bptr2, qs, part);
            reduce_k<<<NB, 256, 0, stream>>>(part, qs, dinv,
                                             probs + (size_t)k * N, qd, N);
            float* t = qs; qs = qd; qd = t;
        }
        mlp2_kernel<<<NBM, 128, 0, stream>>>(probs, W1, b1, W2, b2, out, N);
        return;
    }

    // ---- R6 fallback ----
    const int NBKT = (N + 127) / 128;
    const int NWF  = (E + CHUNK - 1) / CHUNK;
    size_t wordsB = (size_t)2 * E + 2 * (size_t)NBKT + 1 + 19 * (size_t)N + 64;
    size_t wordsA = wordsB + (size_t)E + 2 * (size_t)NBKT + 1;
    bool overlay_ok = (size_t)2 * NWF * NBKT <= (size_t)16 * N;
    bool okA = NBKT <= MAXB && overlay_ok && ws_size >= wordsA * 4;
    bool okB = NBKT <= MAXB && ((size_t)NWF * NBKT <= (size_t)16 * N) && ws_size >= wordsB * 4;

    if (okA || okB) {
        char* p = (char*)d_ws;
        uint2* csr = (uint2*)p;              p += (size_t)E * 8;
        unsigned* degp = nullptr;
        if (okA) { degp = (unsigned*)p;      p += (size_t)E * 4; }
        int* bptrc = (int*)p;                p += (size_t)(NBKT + 1) * 4;
        int* totc  = (int*)p;                p += (size_t)NBKT * 4;
        int* bptrr = nullptr; int* totr = nullptr;
        if (okA) {
            bptrr = (int*)p;                 p += (size_t)(NBKT + 1) * 4;
            totr  = (int*)p;                 p += (size_t)NBKT * 4;
        }
        float* dinv = (float*)p;             p += (size_t)N * 4;
        float* qA   = (float*)p;             p += (size_t)N * 4;
        float* qB   = (float*)p;             p += (size_t)N * 4;
        float* probs = (float*)p;
        int* Cc = (int*)probs;
        int* Cr = Cc + (size_t)NWF * NBKT;

        hist_k<<<NWF, 256, 0, stream>>>(ei, Cc, Cr, NBKT, E, okA ? 1 : 0);
        colscan2_k<<<NBKT, 256, 0, stream>>>(Cc, totc, NBKT, NWF);
        bktscan_k<<<1, 1024, 0, stream>>>(totc, bptrc, NBKT, E);
        if (okA) {
            colscan2_k<<<NBKT, 256, 0, stream>>>(Cr, totr, NBKT, NWF);
            bktscan_k<<<1, 1024, 0, stream>>>(totr, bptrr, NBKT, E);
        }
        scatter_sort_k<<<NWF, 1024, 0, stream>>>(ei, ew, Cc, Cr, bptrc, bptrr,
                                                 csr, degp, NBKT, E, okA ? 1 : 0);
        if (okA) {
            deg_k<<<NBKT, 256, 0, stream>>>(degp, bptrr, dinv, qA, N);
        } else {
            hipMemsetAsync(qB, 0, (size_t)N * 4, stream);
            dega_k<<<(E + 255) / 256, 256, 0, stream>>>(ei, ew, qB, E);
            inv_k<<<NB, 256, 0, stream>>>(qB, dinv, qA, N);
        }
        float* qs = qA; float* qd = qB;
        for (int k = 0; k < WALK; ++k) {
            step_k<<<NBKT, 256, 0, stream>>>(csr, bptrc, qs, dinv,
                                             probs + (size_t)k * N, qd, N);
            float* t = qs; qs = qd; qd = t;
        }
        mlp2_kernel<<<NBM, 128, 0, stream>>>(probs, W1, b1, W2, b2, out, N);
    } else {
        float* deg   = (float*)d_ws;
        float* dinv  = deg + N;
        float* probs = dinv + N;
        hipMemsetAsync(deg, 0, (size_t)N * 4, stream);
        init_push<<<NB, 256, 0, stream>>>(probs, N);
        dega_k<<<(E + 255) / 256, 256, 0, stream>>>(ei, ew, deg, E);
        inv_k<<<NB, 256, 0, stream>>>(deg, dinv, dinv, N);
        for (int k = 0; k < WALK; ++k) {
            step_push<<<(E + N + 255) / 256, 256, 0, stream>>>(
                ei, ew, dinv, probs + (size_t)k * N, probs + (size_t)(k + 1) * N, E, N);
        }
        mlp2_kernel<<<NBM, 128, 0, stream>>>(probs + N, W1, b1, W2, b2, out, N);
    }
}